// Round 1
// baseline (300.971 us; speedup 1.0000x reference)
//
#include <hip/hip_runtime.h>

// ---------------- types ----------------
typedef __bf16 bf16x8 __attribute__((ext_vector_type(8)));
typedef float  f32x4  __attribute__((ext_vector_type(4)));
typedef unsigned short ushort8 __attribute__((ext_vector_type(8)));

#define B_ROWS 8192
#define IN_D   512
#define CTX_D  256
#define CENTER 512
#define MIN_D  768
#define FF_D   1024
#define RNN_D  1024
#define OUT_D  512
#define O2C_D  256
#define TOT_D  768

__device__ __forceinline__ unsigned short f2bf(float f) {
    unsigned int u = __builtin_bit_cast(unsigned int, f);
    u = (u + 0x7fff + ((u >> 16) & 1)) >> 16;   // RNE
    return (unsigned short)u;
}

__device__ __forceinline__ void load_lds16(const void* g, void* l) {
    __builtin_amdgcn_global_load_lds(
        (const __attribute__((address_space(1))) unsigned int*)g,
        (__attribute__((address_space(3))) unsigned int*)l, 16, 0, 0);
}

// ---------------- prep kernels ----------------
__launch_bounds__(256)
__global__ void reduce_sq(const float* __restrict__ w, float* __restrict__ ss, int n) {
    float s = 0.f;
    for (int i = blockIdx.x * blockDim.x + threadIdx.x; i < n; i += gridDim.x * blockDim.x) {
        float v = w[i]; s += v * v;
    }
    #pragma unroll
    for (int off = 32; off > 0; off >>= 1) s += __shfl_down(s, off, 64);
    if ((threadIdx.x & 63) == 0) atomicAdd(ss, s);
}

// W (K x N, fp32, row-major) -> out (N x K bf16 rows, row stride = ostride)
__launch_bounds__(256)
__global__ void cvt_wT(const float* __restrict__ W, unsigned short* __restrict__ out,
                       int K, int N, int ostride, const float* __restrict__ ssp, int total) {
    int g = blockIdx.x * 256 + threadIdx.x;
    if (g >= total) return;
    int n  = g % N;
    int kg = g / N;
    float scale = 1.f;
    if (ssp) scale = 1.f / fmaxf(sqrtf(*ssp), 1.f);
    ushort8 o;
    #pragma unroll
    for (int j = 0; j < 8; ++j)
        o[j] = f2bf(W[(long)(kg * 8 + j) * N + n] * scale);
    *(ushort8*)(out + (long)n * ostride + kg * 8) = o;
}

// fp32 (rows x cols) -> bf16 at out[row*ostride + col]; cols = 1<<logc
__launch_bounds__(256)
__global__ void cvt_act(const float* __restrict__ in, unsigned short* __restrict__ out,
                        int logc, int ostride, long total8) {
    long g = (long)blockIdx.x * 256 + threadIdx.x;
    if (g >= total8) return;
    long e = g * 8;
    long row = e >> logc;
    int  col = (int)(e & ((1 << logc) - 1));
    f32x4 v0 = *(const f32x4*)(in + e);
    f32x4 v1 = *(const f32x4*)(in + e + 4);
    ushort8 o;
    o[0] = f2bf(v0[0]); o[1] = f2bf(v0[1]); o[2] = f2bf(v0[2]); o[3] = f2bf(v0[3]);
    o[4] = f2bf(v1[0]); o[5] = f2bf(v1[1]); o[6] = f2bf(v1[2]); o[7] = f2bf(v1[3]);
    *(ushort8*)(out + row * (long)ostride + col) = o;
}

// ---------------- GEMM ----------------
// C(M x N) = act(A(M x K) @ W^T(N x K)^T + bias)
// A row-major stride K (lda==K always here); Bt: N x K bf16 rows, stride K.
// MODE 0: no bias/act -> bf16 outB        (context)
// MODE 1: bias + relu -> bf16 outB        (pre)
// MODE 2: bias + tanh -> bf16 outB + fp32 outF   (rnn/h_new)
// MODE 3: bias + relu -> fp32 split to d_out regions 0/1   (post)
#define BM 128
#define BN 128
#define BK 32

template<int MODE>
__launch_bounds__(256, 2)
__global__ void gemm_bt(const unsigned short* __restrict__ A,
                        const unsigned short* __restrict__ Bt,
                        int K, const float* __restrict__ bias,
                        unsigned short* __restrict__ outB, int ldob,
                        float* __restrict__ outF, int ldof) {
    __shared__ alignas(16) unsigned short sA[BM * BK];
    __shared__ alignas(16) unsigned short sB[BN * BK];

    const int tid  = threadIdx.x;
    const int wave = tid >> 6;
    const int lane = tid & 63;
    const int bm = blockIdx.x, bn = blockIdx.y;
    const int wm = wave & 1, wn = wave >> 1;

    f32x4 acc[4][4] = {};

    const int lr = lane >> 4;   // quad id
    const int lc = lane & 15;

    for (int k0 = 0; k0 < K; k0 += BK) {
        // stage A and B tiles: 512 chunks of 16B each, 2 per thread per matrix
        #pragma unroll
        for (int j = 0; j < 2; ++j) {
            const int c   = tid + j * 256;
            const int row = c >> 2;
            const int kg  = c & 3;
            const unsigned short* ga = A  + (long)(bm * BM + row) * K + k0 + kg * 8;
            const unsigned short* gb = Bt + (long)(bn * BN + row) * K + k0 + kg * 8;
            load_lds16(ga, (char*)sA + j * 4096 + wave * 1024);
            load_lds16(gb, (char*)sB + j * 4096 + wave * 1024);
        }
        __syncthreads();   // drains vmcnt -> LDS valid

        const unsigned short* pa = sA + (wm * 64 + lc) * BK + lr * 8;
        const unsigned short* pb = sB + (wn * 64 + lc) * BK + lr * 8;
        bf16x8 af[4], bfr[4];
        #pragma unroll
        for (int t = 0; t < 4; ++t) {
            af[t]  = *(const bf16x8*)(pa + t * 16 * BK);
            bfr[t] = *(const bf16x8*)(pb + t * 16 * BK);
        }
        #pragma unroll
        for (int i = 0; i < 4; ++i)
            #pragma unroll
            for (int j2 = 0; j2 < 4; ++j2)
                acc[i][j2] = __builtin_amdgcn_mfma_f32_16x16x32_bf16(af[i], bfr[j2], acc[i][j2], 0, 0, 0);
        __syncthreads();   // LDS reads done before next stage overwrites
    }

    // epilogue: C/D layout col = lane&15, row = (lane>>4)*4 + r
    #pragma unroll
    for (int tn = 0; tn < 4; ++tn) {
        const int gcol = bn * BN + wn * 64 + tn * 16 + lc;
        float bv = 0.f;
        if constexpr (MODE != 0) bv = bias[gcol];
        #pragma unroll
        for (int tm = 0; tm < 4; ++tm) {
            const int grow0 = bm * BM + wm * 64 + tm * 16 + lr * 4;
            #pragma unroll
            for (int r = 0; r < 4; ++r) {
                const long grow = grow0 + r;
                float v = acc[tm][tn][r] + bv;
                if constexpr (MODE == 1 || MODE == 3) v = fmaxf(v, 0.f);
                if constexpr (MODE == 2) v = tanhf(v);
                if constexpr (MODE == 0 || MODE == 1 || MODE == 2)
                    outB[grow * (long)ldob + gcol] = f2bf(v);
                if constexpr (MODE == 2)
                    outF[grow * (long)ldof + gcol] = v;
                if constexpr (MODE == 3) {
                    if (gcol < OUT_D)
                        outF[grow * OUT_D + gcol] = v;
                    else
                        outF[(long)B_ROWS * OUT_D + grow * O2C_D + (gcol - OUT_D)] = v;
                }
            }
        }
    }
}

// ---------------- launch ----------------
extern "C" void kernel_launch(void* const* d_in, const int* in_sizes, int n_in,
                              void* d_out, int out_size, void* d_ws, size_t ws_size,
                              hipStream_t stream) {
    const float* inputs = (const float*)d_in[0];
    const float* center = (const float*)d_in[1];
    const float* mstate = (const float*)d_in[2];
    const float* W_read = (const float*)d_in[3];
    const float* W_pre  = (const float*)d_in[4];
    const float* b_pre  = (const float*)d_in[5];
    const float* Wx     = (const float*)d_in[6];
    const float* Wh     = (const float*)d_in[7];
    const float* b_rnn  = (const float*)d_in[8];
    const float* W_post = (const float*)d_in[9];
    const float* b_post = (const float*)d_in[10];
    float* out = (float*)d_out;

    char* ws = (char*)d_ws;
    float* ss = (float*)ws;
    unsigned short* WreadT = (unsigned short*)(ws + 256);          // 256 x 512
    unsigned short* WpreT  = WreadT + 256 * 512;                   // 1024 x 768
    unsigned short* WxhT   = WpreT  + 1024 * 768;                  // 1024 x 2048
    unsigned short* WpostT = WxhT   + (long)1024 * 2048;           // 768 x 1024
    unsigned short* csB    = WpostT + 768 * 1024;                  // 8192 x 512
    unsigned short* miB    = csB + (long)B_ROWS * CENTER;          // 8192 x 768  [inputs | ctx]
    unsigned short* rnB    = miB + (long)B_ROWS * MIN_D;           // 8192 x 2048 [rnn_in | ms]
    unsigned short* hB     = rnB + (long)B_ROWS * 2048;            // 8192 x 1024

    hipMemsetAsync(ss, 0, 4, stream);
    reduce_sq<<<256, 256, 0, stream>>>(W_read, ss, CENTER * CTX_D);

    // weights -> transposed bf16
    cvt_wT<<<(16384 + 255) / 256, 256, 0, stream>>>(W_read, WreadT, 512, 256, 512, ss, 16384);
    cvt_wT<<<384, 256, 0, stream>>>(W_pre,  WpreT,        768, 1024,  768, nullptr, 98304);
    cvt_wT<<<512, 256, 0, stream>>>(Wx,     WxhT,        1024, 1024, 2048, nullptr, 131072);
    cvt_wT<<<512, 256, 0, stream>>>(Wh,     WxhT + 1024, 1024, 1024, 2048, nullptr, 131072);
    cvt_wT<<<384, 256, 0, stream>>>(W_post, WpostT,      1024,  768, 1024, nullptr, 98304);

    // activations -> bf16 (placed into concat layouts)
    cvt_act<<<2048, 256, 0, stream>>>(center, csB,          9,  512, 524288);
    cvt_act<<<2048, 256, 0, stream>>>(inputs, miB,          9,  768, 524288);
    cvt_act<<<4096, 256, 0, stream>>>(mstate, rnB + 1024,  10, 2048, 1048576);

    // L1: context = cs @ W_clip -> miB cols [512..767]
    gemm_bt<0><<<dim3(64, 2), 256, 0, stream>>>(csB, WreadT, 512, nullptr,
                                                miB + 512, MIN_D, nullptr, 0);
    // L2: rnn_in = relu(mi @ W_pre + b_pre) -> rnB cols [0..1023]
    gemm_bt<1><<<dim3(64, 8), 256, 0, stream>>>(miB, WpreT, 768, b_pre,
                                                rnB, 2048, nullptr, 0);
    // L3: h = tanh([rnn_in|ms] @ [Wx;Wh] + b_rnn) -> hB (bf16) + d_out region 2 (fp32)
    gemm_bt<2><<<dim3(64, 8), 256, 0, stream>>>(rnB, WxhT, 2048, b_rnn,
                                                hB, RNN_D,
                                                out + (long)B_ROWS * TOT_D, RNN_D);
    // L4: module_output = relu(h @ W_post + b_post) -> d_out regions 0/1 (fp32)
    gemm_bt<3><<<dim3(64, 6), 256, 0, stream>>>(hB, WpostT, 1024, b_post,
                                                nullptr, 0, out, 0);
}

// Round 2
// 255.622 us; speedup vs baseline: 1.1774x; 1.1774x over previous
//
#include <hip/hip_runtime.h>

// ---------------- types ----------------
typedef __bf16 bf16x8 __attribute__((ext_vector_type(8)));
typedef float  f32x4  __attribute__((ext_vector_type(4)));
typedef unsigned short ushort8 __attribute__((ext_vector_type(8)));

#define B_ROWS 8192
#define IN_D   512
#define CTX_D  256
#define CENTER 512
#define MIN_D  768
#define FF_D   1024
#define RNN_D  1024
#define OUT_D  512
#define O2C_D  256
#define TOT_D  768

__device__ __forceinline__ unsigned short f2bf(float f) {
    unsigned int u = __builtin_bit_cast(unsigned int, f);
    u = (u + 0x7fff + ((u >> 16) & 1)) >> 16;   // RNE
    return (unsigned short)u;
}

__device__ __forceinline__ void load_lds16(const void* g, void* l) {
    __builtin_amdgcn_global_load_lds(
        (const __attribute__((address_space(1))) unsigned int*)g,
        (__attribute__((address_space(3))) unsigned int*)l, 16, 0, 0);
}

// ---------------- prep kernels ----------------
__launch_bounds__(256)
__global__ void reduce_sq(const float* __restrict__ w, float* __restrict__ ss, int n) {
    float s = 0.f;
    for (int i = blockIdx.x * blockDim.x + threadIdx.x; i < n; i += gridDim.x * blockDim.x) {
        float v = w[i]; s += v * v;
    }
    #pragma unroll
    for (int off = 32; off > 0; off >>= 1) s += __shfl_down(s, off, 64);
    if ((threadIdx.x & 63) == 0) atomicAdd(ss, s);
}

// All weights -> transposed bf16 (N x K rows), one dispatch.
// Segment order: W_pre(98304), Wx(131072), Wh(131072), W_post(98304), W_read(16384)
__launch_bounds__(256)
__global__ void cvt_w_all(const float* __restrict__ Wpre, const float* __restrict__ Wx,
                          const float* __restrict__ Wh,  const float* __restrict__ Wpost,
                          const float* __restrict__ Wread,
                          unsigned short* __restrict__ WpreT, unsigned short* __restrict__ WxhT,
                          unsigned short* __restrict__ WpostT, unsigned short* __restrict__ WreadT) {
    int g = blockIdx.x * 256 + threadIdx.x;
    const float* W; unsigned short* out; int N, ostride;
    if (g < 98304)        { W = Wpre;  out = WpreT;        N = 1024; ostride = 768;  }
    else if (g < 229376)  { g -= 98304;  W = Wx;   out = WxhT;        N = 1024; ostride = 2048; }
    else if (g < 360448)  { g -= 229376; W = Wh;   out = WxhT + 1024; N = 1024; ostride = 2048; }
    else if (g < 458752)  { g -= 360448; W = Wpost; out = WpostT;     N = 768;  ostride = 1024; }
    else                  { g -= 458752; W = Wread; out = WreadT;     N = 256;  ostride = 512;  }
    int n  = g % N;
    int kg = g / N;
    ushort8 o;
    #pragma unroll
    for (int j = 0; j < 8; ++j)
        o[j] = f2bf(W[(long)(kg * 8 + j) * N + n]);
    *(ushort8*)(out + (long)n * ostride + kg * 8) = o;
}

// All activations -> bf16 in concat layouts, one dispatch.
// Segments: center(524288 x8chunks), inputs(524288), mstate(1048576)
__launch_bounds__(256)
__global__ void cvt_act_all(const float* __restrict__ center, const float* __restrict__ inputs,
                            const float* __restrict__ mstate,
                            unsigned short* __restrict__ csB, unsigned short* __restrict__ miB,
                            unsigned short* __restrict__ rnB) {
    long g = (long)blockIdx.x * 256 + threadIdx.x;
    const float* src; unsigned short* dst; int logc, ostride;
    if (g < 524288)       { src = center; dst = csB;        logc = 9;  ostride = 512;  }
    else if (g < 1048576) { g -= 524288;  src = inputs; dst = miB;        logc = 9;  ostride = 768;  }
    else                  { g -= 1048576; src = mstate; dst = rnB + 1024; logc = 10; ostride = 2048; }
    long e = g * 8;
    long row = e >> logc;
    int  col = (int)(e & ((1 << logc) - 1));
    f32x4 v0 = *(const f32x4*)(src + e);
    f32x4 v1 = *(const f32x4*)(src + e + 4);
    ushort8 o;
    o[0] = f2bf(v0[0]); o[1] = f2bf(v0[1]); o[2] = f2bf(v0[2]); o[3] = f2bf(v0[3]);
    o[4] = f2bf(v1[0]); o[5] = f2bf(v1[1]); o[6] = f2bf(v1[2]); o[7] = f2bf(v1[3]);
    *(ushort8*)(dst + row * (long)ostride + col) = o;
}

// ---------------- GEMM ----------------
// C(M x N) = act(A(M x K) @ W^T(N x K)^T [+ bias][* scale])
// Tile: BM=128, BN=64, BK=64. 4 waves: wm=wave&1 (64 rows), wn=wave>>1 (32 cols).
// LDS swizzle: logical 16B chunk (row, kg) stored at chunk slot row*8 + (kg ^ (row&7))
// -> staging thread c fetches global kg = (c&7)^((c>>3)&7); fragment reads are conflict-free.
// MODE 0: *scale(ss) -> bf16 outB            (context; bias ptr = ss)
// MODE 1: bias+relu  -> bf16 outB            (pre)
// MODE 2: bias+tanh  -> bf16 outB + fp32 outF (rnn/h_new)
// MODE 3: bias+relu  -> fp32 split d_out      (post)
template<int MODE>
__launch_bounds__(256, 4)
__global__ void gemm_bt(const unsigned short* __restrict__ A,
                        const unsigned short* __restrict__ Bt,
                        int K, const float* __restrict__ bias,
                        unsigned short* __restrict__ outB, int ldob,
                        float* __restrict__ outF, int ldof) {
    __shared__ alignas(16) unsigned short sA[128 * 64];
    __shared__ alignas(16) unsigned short sB[64 * 64];

    const int tid  = threadIdx.x;
    const int wave = tid >> 6;
    const int lane = tid & 63;
    const int bm = blockIdx.x, bn = blockIdx.y;
    const int wm = wave & 1, wn = wave >> 1;
    const int lr = lane >> 4;   // quad id
    const int lc = lane & 15;
    const int sw = lc & 7;

    f32x4 acc[4][2] = {};

    long aoff[4], boff[2];
    #pragma unroll
    for (int j = 0; j < 4; ++j) {
        const int c   = tid + j * 256;
        const int row = c >> 3;
        const int kg  = (c & 7) ^ (row & 7);
        aoff[j] = (long)(bm * 128 + row) * K + kg * 8;
    }
    #pragma unroll
    for (int j = 0; j < 2; ++j) {
        const int c   = tid + j * 256;
        const int row = c >> 3;
        const int kg  = (c & 7) ^ (row & 7);
        boff[j] = (long)(bn * 64 + row) * K + kg * 8;
    }

    for (int k0 = 0; k0 < K; k0 += 64) {
        #pragma unroll
        for (int j = 0; j < 4; ++j)
            load_lds16(A + aoff[j] + k0, (char*)sA + j * 4096 + wave * 1024);
        #pragma unroll
        for (int j = 0; j < 2; ++j)
            load_lds16(Bt + boff[j] + k0, (char*)sB + j * 4096 + wave * 1024);
        __syncthreads();

        #pragma unroll
        for (int kh = 0; kh < 2; ++kh) {
            const int ch = (kh * 4 + lr) ^ sw;
            bf16x8 af[4], bfr[2];
            #pragma unroll
            for (int t = 0; t < 4; ++t)
                af[t] = *(const bf16x8*)(sA + (wm * 64 + t * 16 + lc) * 64 + ch * 8);
            #pragma unroll
            for (int u = 0; u < 2; ++u)
                bfr[u] = *(const bf16x8*)(sB + (wn * 32 + u * 16 + lc) * 64 + ch * 8);
            #pragma unroll
            for (int i = 0; i < 4; ++i)
                #pragma unroll
                for (int u = 0; u < 2; ++u)
                    acc[i][u] = __builtin_amdgcn_mfma_f32_16x16x32_bf16(af[i], bfr[u], acc[i][u], 0, 0, 0);
        }
        __syncthreads();
    }

    // epilogue: C/D layout col = lane&15, row = (lane>>4)*4 + r
    float sc = 1.f;
    if constexpr (MODE == 0) sc = 1.f / fmaxf(sqrtf(*bias), 1.f);
    #pragma unroll
    for (int u = 0; u < 2; ++u) {
        const int gcol = bn * 64 + wn * 32 + u * 16 + lc;
        float bv = 0.f;
        if constexpr (MODE != 0) bv = bias[gcol];
        #pragma unroll
        for (int tm = 0; tm < 4; ++tm) {
            const int grow0 = bm * 128 + wm * 64 + tm * 16 + lr * 4;
            #pragma unroll
            for (int r = 0; r < 4; ++r) {
                const long grow = grow0 + r;
                float v = acc[tm][u][r];
                if constexpr (MODE == 0) v *= sc;
                else v += bv;
                if constexpr (MODE == 1 || MODE == 3) v = fmaxf(v, 0.f);
                if constexpr (MODE == 2) v = tanhf(v);
                if constexpr (MODE == 0 || MODE == 1 || MODE == 2)
                    outB[grow * (long)ldob + gcol] = f2bf(v);
                if constexpr (MODE == 2)
                    outF[grow * (long)ldof + gcol] = v;
                if constexpr (MODE == 3) {
                    if (gcol < OUT_D)
                        outF[grow * OUT_D + gcol] = v;
                    else
                        outF[(long)B_ROWS * OUT_D + grow * O2C_D + (gcol - OUT_D)] = v;
                }
            }
        }
    }
}

// ---------------- launch ----------------
extern "C" void kernel_launch(void* const* d_in, const int* in_sizes, int n_in,
                              void* d_out, int out_size, void* d_ws, size_t ws_size,
                              hipStream_t stream) {
    const float* inputs = (const float*)d_in[0];
    const float* center = (const float*)d_in[1];
    const float* mstate = (const float*)d_in[2];
    const float* W_read = (const float*)d_in[3];
    const float* W_pre  = (const float*)d_in[4];
    const float* b_pre  = (const float*)d_in[5];
    const float* Wx     = (const float*)d_in[6];
    const float* Wh     = (const float*)d_in[7];
    const float* b_rnn  = (const float*)d_in[8];
    const float* W_post = (const float*)d_in[9];
    const float* b_post = (const float*)d_in[10];
    float* out = (float*)d_out;

    char* ws = (char*)d_ws;
    float* ss = (float*)ws;
    unsigned short* WreadT = (unsigned short*)(ws + 256);          // 256 x 512
    unsigned short* WpreT  = WreadT + 256 * 512;                   // 1024 x 768
    unsigned short* WxhT   = WpreT  + 1024 * 768;                  // 1024 x 2048
    unsigned short* WpostT = WxhT   + (long)1024 * 2048;           // 768 x 1024
    unsigned short* csB    = WpostT + 768 * 1024;                  // 8192 x 512
    unsigned short* miB    = csB + (long)B_ROWS * CENTER;          // 8192 x 768  [inputs | ctx]
    unsigned short* rnB    = miB + (long)B_ROWS * MIN_D;           // 8192 x 2048 [rnn_in | ms]
    unsigned short* hB     = rnB + (long)B_ROWS * 2048;            // 8192 x 1024

    hipMemsetAsync(ss, 0, 4, stream);
    reduce_sq<<<128, 256, 0, stream>>>(W_read, ss, CENTER * CTX_D);

    // all weights -> transposed bf16, one dispatch (475136 chunks)
    cvt_w_all<<<1856, 256, 0, stream>>>(W_pre, Wx, Wh, W_post, W_read,
                                        WpreT, WxhT, WpostT, WreadT);
    // all activations -> bf16 concat layouts, one dispatch (2097152 chunks)
    cvt_act_all<<<8192, 256, 0, stream>>>(center, inputs, mstate, csB, miB, rnB);

    // L1: context = (cs @ W_read) * clipscale -> miB cols [512..767]
    gemm_bt<0><<<dim3(64, 4), 256, 0, stream>>>(csB, WreadT, 512, ss,
                                                miB + 512, MIN_D, nullptr, 0);
    // L2: rnn_in = relu(mi @ W_pre + b_pre) -> rnB cols [0..1023]
    gemm_bt<1><<<dim3(64, 16), 256, 0, stream>>>(miB, WpreT, 768, b_pre,
                                                 rnB, 2048, nullptr, 0);
    // L3: h = tanh([rnn_in|ms] @ [Wx;Wh] + b_rnn) -> hB (bf16) + d_out region 2 (fp32)
    gemm_bt<2><<<dim3(64, 16), 256, 0, stream>>>(rnB, WxhT, 2048, b_rnn,
                                                 hB, RNN_D,
                                                 out + (long)B_ROWS * TOT_D, RNN_D);
    // L4: module_output = relu(h @ W_post + b_post) -> d_out regions 0/1 (fp32)
    gemm_bt<3><<<dim3(64, 12), 256, 0, stream>>>(hB, WpostT, 1024, b_post,
                                                 nullptr, 0, out, 0);
}